// Round 1
// baseline (1409.621 us; speedup 1.0000x reference)
//
#include <hip/hip_runtime.h>
#include <hip/hip_bf16.h>
#include <stdint.h>

// Problem constants (from reference): H=2048, I=4096, E=8, TOPK=2, B*S=4096
#define H_DIM 2048
#define I_DIM 4096
#define NEXP  8
#define NTOK  4096
#define NPAIR 8192                 // NTOK * TOPK
#define PAD_ROWS (NPAIR + 128)     // pad so last 128-row tile of last expert stays in-bounds

// Workspace layout (bytes)
#define WS_COUNTS   0ull
#define WS_OFFSETS  256ull
#define WS_TOKID    1024ull                         // NPAIR ints
#define WS_PAIRW    (64ull * 1024)                  // NPAIR floats
#define WS_XG       (1ull * 1024 * 1024)            // PAD_ROWS * H * 2B = 34.1 MB
#define WS_INTER    (40ull * 1024 * 1024)           // PAD_ROWS * I * 2B = 68.2 MB
#define WS_NEEDED   (WS_INTER + (unsigned long long)PAD_ROWS * I_DIM * 2)

typedef __attribute__((ext_vector_type(8))) short bf16x8;   // 8 bf16 = 4 VGPRs (MFMA A/B frag)
typedef __attribute__((ext_vector_type(4))) float f32x4;    // MFMA C/D frag

#if defined(__has_builtin)
#if __has_builtin(__builtin_amdgcn_cvt_pk_bf16_f32)
#define HAVE_CVT_PK 1
#endif
#endif

__device__ __forceinline__ uint32_t bf16_bits_rne(float x) {
  uint32_t u = __float_as_uint(x);
  return (u + 0x7FFFu + ((u >> 16) & 1u)) >> 16;
}

__device__ __forceinline__ uint32_t pk_bf16(float a, float b) {
#ifdef HAVE_CVT_PK
  auto r = __builtin_amdgcn_cvt_pk_bf16_f32(a, b);   // v_cvt_pk_bf16_f32 (RNE), 1 instr / 2 elems
  return __builtin_bit_cast(uint32_t, r);
#else
  return bf16_bits_rne(a) | (bf16_bits_rne(b) << 16);
#endif
}

__device__ __forceinline__ uint16_t bf16_one(float x) {
  return (uint16_t)(pk_bf16(x, x) & 0xFFFFu);
}

// async global->LDS, 16B per lane; lds base must be wave-uniform, lane i lands at base + 16*i
__device__ __forceinline__ void async_load16(const void* g, void* l) {
  __builtin_amdgcn_global_load_lds(
      (const __attribute__((address_space(1))) void*)g,
      (__attribute__((address_space(3))) void*)l, 16, 0, 0);
}

// ---------------- routing: counts, offsets, scatter (token_id, pair_w) ----------------
__global__ void route_kernel(const int* __restrict__ idx, const float* __restrict__ wts,
                             int* __restrict__ ws_counts, int* __restrict__ ws_offsets,
                             int* __restrict__ tokid, float* __restrict__ pairw) {
  __shared__ int s_cnt[NEXP], s_off[NEXP], s_cur[NEXP];
  int tid = threadIdx.x;
  if (tid < NEXP) s_cnt[tid] = 0;
  __syncthreads();
  for (int p = tid; p < NPAIR; p += 256) atomicAdd(&s_cnt[idx[p]], 1);
  __syncthreads();
  if (tid == 0) {
    int acc = 0;
    for (int e = 0; e < NEXP; e++) { s_off[e] = acc; s_cur[e] = acc; acc += s_cnt[e]; }
  }
  __syncthreads();
  for (int p = tid; p < NPAIR; p += 256) {
    int e = idx[p];
    int slot = atomicAdd(&s_cur[e], 1);     // slot already includes expert base offset
    tokid[slot] = p >> 1;                   // TOPK = 2
    pairw[slot] = wts[p];
  }
  if (tid < NEXP) { ws_counts[tid] = s_cnt[tid]; ws_offsets[tid] = s_off[tid]; }
}

// ---------------- gather routed rows of x, fp32 -> bf16 ----------------
__global__ void gather_cast_kernel(const float* __restrict__ x, const int* __restrict__ tokid,
                                   uint16_t* __restrict__ xg) {
  int p = blockIdx.x;                  // routed row
  int t = tokid[p];
  int c = threadIdx.x * 8;             // 256 threads * 8 = 2048 = H
  const float4* src = (const float4*)(x + (size_t)t * H_DIM + c);
  float4 v0 = src[0], v1 = src[1];
  uint4 o;
  o.x = pk_bf16(v0.x, v0.y); o.y = pk_bf16(v0.z, v0.w);
  o.z = pk_bf16(v1.x, v1.y); o.w = pk_bf16(v1.z, v1.w);
  *(uint4*)(xg + (size_t)p * H_DIM + c) = o;
}

// ---------------- GEMM1: [rows,H] x {gate,up}[I,H]^T -> silu(g)*u -> inter[rows,I] bf16 ----------------
// block 256 = 4 waves (2x2 of 64x64), tile 128x128, BK=64
__global__ __launch_bounds__(256, 2)
void gemm1_kernel(const uint16_t* __restrict__ xg,
                  const float* __restrict__ gate, const float* __restrict__ up,
                  const int* __restrict__ ws_counts, const int* __restrict__ ws_offsets,
                  uint16_t* __restrict__ inter) {
  int e = blockIdx.z;
  int cnt = ws_counts[e];
  int rowTile = blockIdx.y;
  if (rowTile * 128 >= cnt) return;
  int off = ws_offsets[e];
  int colBase = blockIdx.x * 128;
  size_t rowBase = (size_t)off + (size_t)rowTile * 128;

  __shared__ uint16_t lA[128 * 64];
  __shared__ uint16_t lBg[128 * 64];
  __shared__ uint16_t lBu[128 * 64];

  int tid = threadIdx.x;
  int lane = tid & 63, wid = tid >> 6;
  int wm = (wid & 1) * 64, wn = (wid >> 1) * 64;
  int lcol = lane & 15, quad = lane >> 4;

  const float* gbase = gate + (size_t)e * I_DIM * H_DIM + (size_t)colBase * H_DIM;
  const float* ubase = up   + (size_t)e * I_DIM * H_DIM + (size_t)colBase * H_DIM;

  f32x4 accg[4][4], accu[4][4];
  f32x4 zero = {0.f, 0.f, 0.f, 0.f};
#pragma unroll
  for (int mi = 0; mi < 4; mi++)
#pragma unroll
    for (int ni = 0; ni < 4; ni++) { accg[mi][ni] = zero; accu[mi][ni] = zero; }

  for (int k0 = 0; k0 < H_DIM; k0 += 64) {
    __syncthreads();
    // A tile via async global->LDS (bf16 source, contiguous routed rows)
#pragma unroll
    for (int rd = 0; rd < 4; rd++) {
      int chunkBase = rd * 256 + wid * 64;           // wave-uniform
      int chunk = chunkBase + lane;
      int row = chunk >> 3, kc = (chunk & 7) * 8;
      async_load16(xg + (rowBase + row) * H_DIM + k0 + kc, lA + chunkBase * 8);
    }
    // B tiles (gate, up): fp32 -> bf16 on the fly
#pragma unroll
    for (int it = 0; it < 4; it++) {
      int c = it * 256 + tid;
      int row = c >> 3, kc = (c & 7) * 8;
      size_t soff = (size_t)row * H_DIM + k0 + kc;
      const float4* sg = (const float4*)(gbase + soff);
      float4 g0 = sg[0], g1 = sg[1];
      const float4* su = (const float4*)(ubase + soff);
      float4 u0 = su[0], u1 = su[1];
      uint4 og = { pk_bf16(g0.x, g0.y), pk_bf16(g0.z, g0.w), pk_bf16(g1.x, g1.y), pk_bf16(g1.z, g1.w) };
      uint4 ou = { pk_bf16(u0.x, u0.y), pk_bf16(u0.z, u0.w), pk_bf16(u1.x, u1.y), pk_bf16(u1.z, u1.w) };
      *(uint4*)(lBg + c * 8) = og;
      *(uint4*)(lBu + c * 8) = ou;
    }
    __syncthreads();
#pragma unroll
    for (int ks = 0; ks < 64; ks += 32) {
      int krow = ks + quad * 8;
      bf16x8 af[4], bg[4], bu[4];
#pragma unroll
      for (int mi = 0; mi < 4; mi++)
        af[mi] = *(const bf16x8*)(lA + (wm + mi * 16 + lcol) * 64 + krow);
#pragma unroll
      for (int ni = 0; ni < 4; ni++) {
        bg[ni] = *(const bf16x8*)(lBg + (wn + ni * 16 + lcol) * 64 + krow);
        bu[ni] = *(const bf16x8*)(lBu + (wn + ni * 16 + lcol) * 64 + krow);
      }
#pragma unroll
      for (int mi = 0; mi < 4; mi++)
#pragma unroll
        for (int ni = 0; ni < 4; ni++) {
          accg[mi][ni] = __builtin_amdgcn_mfma_f32_16x16x32_bf16(af[mi], bg[ni], accg[mi][ni], 0, 0, 0);
          accu[mi][ni] = __builtin_amdgcn_mfma_f32_16x16x32_bf16(af[mi], bu[ni], accu[mi][ni], 0, 0, 0);
        }
    }
  }
  // epilogue: silu(g)*u -> bf16 inter.  C layout: col=lane&15, row=quad*4+reg
  int col0 = colBase + wn;
#pragma unroll
  for (int mi = 0; mi < 4; mi++) {
#pragma unroll
    for (int r = 0; r < 4; r++) {
      int localRow = rowTile * 128 + wm + mi * 16 + quad * 4 + r;
      if (localRow < cnt) {
        size_t prow = (size_t)off + localRow;
#pragma unroll
        for (int ni = 0; ni < 4; ni++) {
          float g = accg[mi][ni][r], u = accu[mi][ni][r];
          float v = (g / (1.f + __expf(-g))) * u;
          inter[prow * I_DIM + col0 + ni * 16 + lcol] = bf16_one(v);
        }
      }
    }
  }
}

// ---------------- GEMM2: inter[rows,I] x down[H,I]^T -> weighted atomic add to out ----------------
__global__ __launch_bounds__(256, 2)
void gemm2_kernel(const uint16_t* __restrict__ inter, const float* __restrict__ down,
                  const int* __restrict__ ws_counts, const int* __restrict__ ws_offsets,
                  const int* __restrict__ tokid, const float* __restrict__ pairw,
                  float* __restrict__ out) {
  int e = blockIdx.z;
  int cnt = ws_counts[e];
  int rowTile = blockIdx.y;
  if (rowTile * 128 >= cnt) return;
  int off = ws_offsets[e];
  int colBase = blockIdx.x * 128;
  size_t rowBase = (size_t)off + (size_t)rowTile * 128;

  __shared__ uint16_t lA[128 * 64];
  __shared__ uint16_t lB[128 * 64];

  int tid = threadIdx.x;
  int lane = tid & 63, wid = tid >> 6;
  int wm = (wid & 1) * 64, wn = (wid >> 1) * 64;
  int lcol = lane & 15, quad = lane >> 4;

  const float* dbase = down + (size_t)e * H_DIM * I_DIM + (size_t)colBase * I_DIM;

  f32x4 acc[4][4];
  f32x4 zero = {0.f, 0.f, 0.f, 0.f};
#pragma unroll
  for (int mi = 0; mi < 4; mi++)
#pragma unroll
    for (int ni = 0; ni < 4; ni++) acc[mi][ni] = zero;

  for (int k0 = 0; k0 < I_DIM; k0 += 64) {
    __syncthreads();
#pragma unroll
    for (int rd = 0; rd < 4; rd++) {
      int chunkBase = rd * 256 + wid * 64;
      int chunk = chunkBase + lane;
      int row = chunk >> 3, kc = (chunk & 7) * 8;
      async_load16(inter + (rowBase + row) * I_DIM + k0 + kc, lA + chunkBase * 8);
    }
#pragma unroll
    for (int it = 0; it < 4; it++) {
      int c = it * 256 + tid;
      int row = c >> 3, kc = (c & 7) * 8;
      const float4* sd = (const float4*)(dbase + (size_t)row * I_DIM + k0 + kc);
      float4 d0 = sd[0], d1 = sd[1];
      uint4 od = { pk_bf16(d0.x, d0.y), pk_bf16(d0.z, d0.w), pk_bf16(d1.x, d1.y), pk_bf16(d1.z, d1.w) };
      *(uint4*)(lB + c * 8) = od;
    }
    __syncthreads();
#pragma unroll
    for (int ks = 0; ks < 64; ks += 32) {
      int krow = ks + quad * 8;
      bf16x8 af[4], bf[4];
#pragma unroll
      for (int mi = 0; mi < 4; mi++)
        af[mi] = *(const bf16x8*)(lA + (wm + mi * 16 + lcol) * 64 + krow);
#pragma unroll
      for (int ni = 0; ni < 4; ni++)
        bf[ni] = *(const bf16x8*)(lB + (wn + ni * 16 + lcol) * 64 + krow);
#pragma unroll
      for (int mi = 0; mi < 4; mi++)
#pragma unroll
        for (int ni = 0; ni < 4; ni++)
          acc[mi][ni] = __builtin_amdgcn_mfma_f32_16x16x32_bf16(af[mi], bf[ni], acc[mi][ni], 0, 0, 0);
    }
  }
  int col0 = colBase + wn;
#pragma unroll
  for (int mi = 0; mi < 4; mi++) {
#pragma unroll
    for (int r = 0; r < 4; r++) {
      int localRow = rowTile * 128 + wm + mi * 16 + quad * 4 + r;
      if (localRow < cnt) {
        size_t prow = (size_t)off + localRow;
        int t = tokid[prow];
        float w = pairw[prow];
        float* orow = out + (size_t)t * H_DIM + col0;
#pragma unroll
        for (int ni = 0; ni < 4; ni++)
          atomicAdd(orow + ni * 16 + lcol, acc[mi][ni][r] * w);
      }
    }
  }
}

extern "C" void kernel_launch(void* const* d_in, const int* in_sizes, int n_in,
                              void* d_out, int out_size, void* d_ws, size_t ws_size,
                              hipStream_t stream) {
  const float* x    = (const float*)d_in[0];
  const int*   eidx = (const int*)d_in[1];
  const float* ew   = (const float*)d_in[2];
  const float* gate = (const float*)d_in[3];
  const float* up   = (const float*)d_in[4];
  const float* down = (const float*)d_in[5];
  float* out = (float*)d_out;
  char* ws = (char*)d_ws;

  if (ws_size < WS_NEEDED) {
    // workspace too small: zero output so failure is a clean absmax miss, not corruption
    hipMemsetAsync(d_out, 0, (size_t)NTOK * H_DIM * sizeof(float), stream);
    return;
  }

  int*      counts  = (int*)(ws + WS_COUNTS);
  int*      offsets = (int*)(ws + WS_OFFSETS);
  int*      tokid   = (int*)(ws + WS_TOKID);
  float*    pairw   = (float*)(ws + WS_PAIRW);
  uint16_t* xg      = (uint16_t*)(ws + WS_XG);
  uint16_t* inter   = (uint16_t*)(ws + WS_INTER);

  hipMemsetAsync(d_out, 0, (size_t)NTOK * H_DIM * sizeof(float), stream);
  route_kernel<<<1, 256, 0, stream>>>(eidx, ew, counts, offsets, tokid, pairw);
  gather_cast_kernel<<<NPAIR, 256, 0, stream>>>(x, tokid, xg);
  gemm1_kernel<<<dim3(I_DIM / 128, NPAIR / 128, NEXP), 256, 0, stream>>>(
      xg, gate, up, counts, offsets, inter);
  gemm2_kernel<<<dim3(H_DIM / 128, NPAIR / 128, NEXP), 256, 0, stream>>>(
      inter, down, counts, offsets, tokid, pairw, out);
}